// Round 1
// baseline (307.849 us; speedup 1.0000x reference)
//
#include <hip/hip_runtime.h>
#include <math.h>

// Problem constants
#define BATCH 4096
#define NFEAT 2048
#define NNEUR 1024
#define NTGT  8
#define NNZ1  65536
#define NNZ2  8192

struct __align__(8) Edge { float w; int c; };

// ---------------- workspace layout (bytes) ----------------
// xT : [NFEAT][BATCH] f32   32 MB
// hT : [NNEUR][BATCH] f32   16 MB
// e1 : NNZ1 Edge            512 KB
// e2 : NNZ2 Edge            64 KB
// rp1: NNEUR+1 int, cur1: NNEUR int, rp2/cur2/cnt1/cnt2 small
// total ~48.7 MB (assumes ws_size is at least this; typical harness ws is larger)
#define OFF_XT   ((size_t)0)
#define OFF_HT   ((size_t)33554432)
#define OFF_E1   ((size_t)50331648)
#define OFF_E2   ((size_t)50855936)
#define OFF_RP1  ((size_t)50921472)   // (NNEUR+1)*4, padded
#define OFF_CUR1 ((size_t)50926080)
#define OFF_RP2  ((size_t)50930432)
#define OFF_CUR2 ((size_t)50930688)
#define OFF_CNT1 ((size_t)50930944)
#define OFF_CNT2 ((size_t)50935296)

__global__ void k_zero(int* __restrict__ cnt1, int* __restrict__ cnt2) {
    int i = blockIdx.x * blockDim.x + threadIdx.x;
    if (i < NNEUR) cnt1[i] = 0;
    if (i < NTGT)  cnt2[i] = 0;
}

__global__ void k_hist(const int* __restrict__ c1o, const int* __restrict__ c2o,
                       int* __restrict__ cnt1, int* __restrict__ cnt2) {
    int i = blockIdx.x * blockDim.x + threadIdx.x;
    if (i < NNZ1) {
        atomicAdd(&cnt1[c1o[i]], 1);
    } else {
        int j = i - NNZ1;
        if (j < NNZ2) atomicAdd(&cnt2[c2o[j]], 1);
    }
}

// single block, 1024 threads: exclusive scan of cnt1 -> rp1/cur1; serial scan cnt2 -> rp2/cur2
__global__ void k_scan(const int* __restrict__ cnt1, const int* __restrict__ cnt2,
                       int* __restrict__ rp1, int* __restrict__ cur1,
                       int* __restrict__ rp2, int* __restrict__ cur2) {
    __shared__ int s[2][NNEUR];
    int t = threadIdx.x;
    s[0][t] = cnt1[t];
    __syncthreads();
    int src = 0;
    for (int off = 1; off < NNEUR; off <<= 1) {
        int v = s[src][t];
        if (t >= off) v += s[src][t - off];
        s[src ^ 1][t] = v;
        __syncthreads();
        src ^= 1;
    }
    int excl = (t == 0) ? 0 : s[src][t - 1];
    rp1[t]  = excl;
    cur1[t] = excl;
    if (t == 0) {
        rp1[NNEUR] = s[src][NNEUR - 1];
        int run = 0;
        for (int i = 0; i < NTGT; ++i) { rp2[i] = run; cur2[i] = run; run += cnt2[i]; }
        rp2[NTGT] = run;
    }
}

__global__ void k_scatter(const float* __restrict__ w1, const int* __restrict__ c1o, const int* __restrict__ c1i,
                          const float* __restrict__ w2, const int* __restrict__ c2o, const int* __restrict__ c2i,
                          int* __restrict__ cur1, int* __restrict__ cur2,
                          Edge* __restrict__ e1, Edge* __restrict__ e2) {
    int i = blockIdx.x * blockDim.x + threadIdx.x;
    if (i < NNZ1) {
        int r = c1o[i];
        int p = atomicAdd(&cur1[r], 1);
        Edge ed; ed.w = w1[i]; ed.c = c1i[i];
        e1[p] = ed;
    } else {
        int j = i - NNZ1;
        if (j < NNZ2) {
            int r = c2o[j];
            int p = atomicAdd(&cur2[r], 1);
            Edge ed; ed.w = w2[j]; ed.c = c2i[j];
            e2[p] = ed;
        }
    }
}

// x [BATCH][NFEAT] -> xT [NFEAT][BATCH]; 32x32 tiles, block (32,8)
__global__ void k_transpose(const float* __restrict__ x, float* __restrict__ xT) {
    __shared__ float tile[32][33];
    int f0 = blockIdx.x * 32;
    int b0 = blockIdx.y * 32;
    int tx = threadIdx.x, ty = threadIdx.y;
#pragma unroll
    for (int i = 0; i < 4; ++i)
        tile[ty + i * 8][tx] = x[(size_t)(b0 + ty + i * 8) * NFEAT + f0 + tx];
    __syncthreads();
#pragma unroll
    for (int i = 0; i < 4; ++i)
        xT[(size_t)(f0 + ty + i * 8) * BATCH + b0 + tx] = tile[tx][ty + i * 8];
}

// grid 1024 blocks (64 batch tiles x 16 neuron groups), block 256 (4 waves).
// wave owns 16 neurons sequentially; lane = batch row within 64-wide tile.
__global__ __launch_bounds__(256) void k_layer1(const Edge* __restrict__ e1,
                                                const int* __restrict__ rp1,
                                                const float* __restrict__ b1,
                                                const float* __restrict__ xT,
                                                float* __restrict__ hT) {
    const int NG = 16;
    // XCD swizzle: all 16 neuron-group blocks of one batch tile land on one XCD
    int bid = blockIdx.x;
    int xcd = bid & 7;
    int i = bid >> 3;              // [0,128) per xcd
    int bt = xcd * 8 + (i >> 4);   // 8 batch tiles per xcd
    int g = i & 15;
    int wave = __builtin_amdgcn_readfirstlane((int)(threadIdx.x >> 6));
    int lane = threadIdx.x & 63;
    int b = bt * 64 + lane;
    int n0 = g * 64 + wave * 16;
    for (int ni = 0; ni < 16; ++ni) {
        int n = n0 + ni;
        int s = rp1[n], e = rp1[n + 1];
        float acc = 0.f;
#pragma unroll 4
        for (int k = s; k < e; ++k) {
            Edge ed = e1[k];
            acc += ed.w * xT[(size_t)ed.c * BATCH + b];
        }
        float z = acc + b1[n];
        hT[(size_t)n * BATCH + b] = 1.f / (1.f + __expf(-z));
    }
}

// grid 512 blocks (64 batch tiles x 8 targets), block 256 (4 waves split the edge list)
__global__ __launch_bounds__(256) void k_layer2(const Edge* __restrict__ e2,
                                                const int* __restrict__ rp2,
                                                const float* __restrict__ b2,
                                                const float* __restrict__ hT,
                                                float* __restrict__ out) {
    __shared__ float part[4][64];
    int bid = blockIdx.x;
    int bt = bid >> 3;
    int t = bid & 7;
    int wave = threadIdx.x >> 6;
    int lane = threadIdx.x & 63;
    int b = bt * 64 + lane;
    int s = rp2[t], e = rp2[t + 1];
    float acc = 0.f;
    for (int k = s + wave; k < e; k += 4) {
        Edge ed = e2[k];
        acc += ed.w * hT[(size_t)ed.c * BATCH + b];
    }
    part[wave][lane] = acc;
    __syncthreads();
    if (wave == 0) {
        float tot = part[0][lane] + part[1][lane] + part[2][lane] + part[3][lane];
        out[(size_t)b * NTGT + t] = tot + b2[t];
    }
}

extern "C" void kernel_launch(void* const* d_in, const int* in_sizes, int n_in,
                              void* d_out, int out_size, void* d_ws, size_t ws_size,
                              hipStream_t stream) {
    (void)in_sizes; (void)n_in; (void)out_size; (void)ws_size;
    const float* x   = (const float*)d_in[0];
    const float* w1  = (const float*)d_in[1];
    const float* b1  = (const float*)d_in[2];
    const float* w2  = (const float*)d_in[3];
    const float* b2  = (const float*)d_in[4];
    const int*   c1o = (const int*)d_in[5];
    const int*   c1i = (const int*)d_in[6];
    const int*   c2o = (const int*)d_in[7];
    const int*   c2i = (const int*)d_in[8];
    float* out = (float*)d_out;

    char* ws = (char*)d_ws;
    float* xT   = (float*)(ws + OFF_XT);
    float* hT   = (float*)(ws + OFF_HT);
    Edge*  e1   = (Edge*)(ws + OFF_E1);
    Edge*  e2   = (Edge*)(ws + OFF_E2);
    int*   rp1  = (int*)(ws + OFF_RP1);
    int*   cur1 = (int*)(ws + OFF_CUR1);
    int*   rp2  = (int*)(ws + OFF_RP2);
    int*   cur2 = (int*)(ws + OFF_CUR2);
    int*   cnt1 = (int*)(ws + OFF_CNT1);
    int*   cnt2 = (int*)(ws + OFF_CNT2);

    // CSR build (deterministic up to within-segment order; fp32 reorder noise << threshold)
    k_zero<<<4, 256, 0, stream>>>(cnt1, cnt2);
    k_hist<<<(NNZ1 + NNZ2) / 256, 256, 0, stream>>>(c1o, c2o, cnt1, cnt2);
    k_scan<<<1, NNEUR, 0, stream>>>(cnt1, cnt2, rp1, cur1, rp2, cur2);
    k_scatter<<<(NNZ1 + NNZ2) / 256, 256, 0, stream>>>(w1, c1o, c1i, w2, c2o, c2i, cur1, cur2, e1, e2);

    // transpose x for coalesced lane=batch gathers
    k_transpose<<<dim3(NFEAT / 32, BATCH / 32), dim3(32, 8), 0, stream>>>(x, xT);

    // layer 1: 64 batch tiles x 16 neuron groups
    k_layer1<<<64 * 16, 256, 0, stream>>>(e1, rp1, b1, xT, hT);

    // layer 2: 64 batch tiles x 8 targets
    k_layer2<<<64 * 8, 256, 0, stream>>>(e2, rp2, b2, hT, out);
}

// Round 2
// 139.363 us; speedup vs baseline: 2.2090x; 2.2090x over previous
//
#include <hip/hip_runtime.h>
#include <math.h>

// Problem constants
#define BATCH 4096
#define NFEAT 2048
#define NNEUR 1024
#define NTGT  8
#define NNZ1  65536
#define NNZ2  8192

struct __align__(8) Edge { float w; int c; };

// ---------------- workspace layout (bytes) ----------------
// xT   : [NFEAT][BATCH] f32                 32 MB
// part : [32][BATCH][NTGT] f32               4 MB
// e1   : NNZ1 Edge                          512 KB
// W2d  : [NNEUR][NTGT] f32                   32 KB
// rp1/cur1/cnt1 : small ints
#define OFF_XT   ((size_t)0)
#define OFF_PART ((size_t)33554432)          // 32 MB
#define OFF_E1   ((size_t)37748736)          // 36 MB
#define OFF_W2D  ((size_t)38273024)          // 36.5 MB
#define OFF_RP1  ((size_t)38305792)
#define OFF_CUR1 ((size_t)38313984)
#define OFF_CNT1 ((size_t)38322176)

__global__ void k_zero(int* __restrict__ cnt1, float* __restrict__ W2d) {
    int i = blockIdx.x * blockDim.x + threadIdx.x;
    if (i < NNEUR) cnt1[i] = 0;
    if (i < NNEUR * NTGT) W2d[i] = 0.f;
}

// histogram layer-1 rows; build dense W2 (handles duplicate (t,n) edges by summing)
__global__ void k_hist(const int* __restrict__ c1o,
                       const int* __restrict__ c2o, const int* __restrict__ c2i,
                       const float* __restrict__ w2,
                       int* __restrict__ cnt1, float* __restrict__ W2d) {
    int i = blockIdx.x * blockDim.x + threadIdx.x;
    if (i < NNZ1) {
        atomicAdd(&cnt1[c1o[i]], 1);
    } else {
        int j = i - NNZ1;
        if (j < NNZ2) atomicAdd(&W2d[c2i[j] * NTGT + c2o[j]], w2[j]);
    }
}

// single block, 1024 threads: exclusive scan of cnt1 -> rp1/cur1
__global__ void k_scan(const int* __restrict__ cnt1,
                       int* __restrict__ rp1, int* __restrict__ cur1) {
    __shared__ int s[2][NNEUR];
    int t = threadIdx.x;
    s[0][t] = cnt1[t];
    __syncthreads();
    int src = 0;
    for (int off = 1; off < NNEUR; off <<= 1) {
        int v = s[src][t];
        if (t >= off) v += s[src][t - off];
        s[src ^ 1][t] = v;
        __syncthreads();
        src ^= 1;
    }
    int excl = (t == 0) ? 0 : s[src][t - 1];
    rp1[t]  = excl;
    cur1[t] = excl;
    if (t == 0) rp1[NNEUR] = s[src][NNEUR - 1];
}

__global__ void k_scatter(const float* __restrict__ w1, const int* __restrict__ c1o,
                          const int* __restrict__ c1i,
                          int* __restrict__ cur1, Edge* __restrict__ e1) {
    int i = blockIdx.x * blockDim.x + threadIdx.x;
    if (i < NNZ1) {
        int r = c1o[i];
        int p = atomicAdd(&cur1[r], 1);
        Edge ed; ed.w = w1[i]; ed.c = c1i[i];
        e1[p] = ed;
    }
}

// x [BATCH][NFEAT] -> xT [NFEAT][BATCH]; 64x64 tiles, float4 both sides, block (16,16)
__global__ void k_transpose(const float* __restrict__ x, float* __restrict__ xT) {
    __shared__ float tile[64][68];
    int f0 = blockIdx.x * 64;
    int b0 = blockIdx.y * 64;
    int tx = threadIdx.x, ty = threadIdx.y;
#pragma unroll
    for (int r = 0; r < 4; ++r) {
        int row = ty + r * 16;  // b-local
        float4 v = *(const float4*)&x[(size_t)(b0 + row) * NFEAT + f0 + tx * 4];
        tile[row][tx * 4 + 0] = v.x;
        tile[row][tx * 4 + 1] = v.y;
        tile[row][tx * 4 + 2] = v.z;
        tile[row][tx * 4 + 3] = v.w;
    }
    __syncthreads();
#pragma unroll
    for (int r = 0; r < 4; ++r) {
        int frow = ty + r * 16;  // f-local
        float4 v;
        v.x = tile[tx * 4 + 0][frow];
        v.y = tile[tx * 4 + 1][frow];
        v.z = tile[tx * 4 + 2][frow];
        v.w = tile[tx * 4 + 3][frow];
        *(float4*)&xT[(size_t)(f0 + frow) * BATCH + b0 + tx * 4] = v;
    }
}

// Fused layer1 (sparse) + sigmoid + layer2 (dense W2d) partials.
// Grid: 512 blocks = 16 batch tiles (256 rows) x 32 neuron groups (32 neurons).
// Block: 256 threads = 4 waves; wave owns 8 neurons; lane owns 4 batch rows (float4).
// XCD swizzle: each XCD gets 2 batch tiles x 32 groups -> x footprint 4MB = its L2.
__global__ __launch_bounds__(256) void k_layer1_fused(
        const Edge* __restrict__ e1, const int* __restrict__ rp1,
        const float* __restrict__ b1, const float* __restrict__ W2d,
        const float* __restrict__ xT, float* __restrict__ part) {
    int bid = blockIdx.x;
    int xcd = bid & 7;
    int i = bid >> 3;              // [0,64) per xcd
    int bt = xcd * 2 + (i >> 5);   // 2 batch tiles per xcd
    int g = i & 31;                // neuron group
    int wave = threadIdx.x >> 6;
    int lane = threadIdx.x & 63;
    int b4 = bt * 256 + lane * 4;

    float4 accT[NTGT];
#pragma unroll
    for (int t = 0; t < NTGT; ++t) accT[t] = make_float4(0.f, 0.f, 0.f, 0.f);

    int n0 = g * 32 + wave * 8;
    for (int ni = 0; ni < 8; ++ni) {
        int n = n0 + ni;
        int s = rp1[n], e = rp1[n + 1];
        float4 acc = make_float4(0.f, 0.f, 0.f, 0.f);
#pragma unroll 4
        for (int k = s; k < e; ++k) {
            Edge ed = e1[k];
            float4 xv = *(const float4*)&xT[(size_t)ed.c * BATCH + b4];
            acc.x += ed.w * xv.x;
            acc.y += ed.w * xv.y;
            acc.z += ed.w * xv.z;
            acc.w += ed.w * xv.w;
        }
        float bn = b1[n];
        float4 h;
        h.x = 1.f / (1.f + __expf(-(acc.x + bn)));
        h.y = 1.f / (1.f + __expf(-(acc.y + bn)));
        h.z = 1.f / (1.f + __expf(-(acc.z + bn)));
        h.w = 1.f / (1.f + __expf(-(acc.w + bn)));
        const float* w2row = &W2d[n * NTGT];
#pragma unroll
        for (int t = 0; t < NTGT; ++t) {
            float wv = w2row[t];
            accT[t].x += wv * h.x;
            accT[t].y += wv * h.y;
            accT[t].z += wv * h.z;
            accT[t].w += wv * h.w;
        }
    }

    // cross-wave reduce via LDS (rotated elem index to avoid bank conflicts)
    __shared__ float s_part[4][64][32];
#pragma unroll
    for (int t = 0; t < NTGT; ++t) {
        s_part[wave][lane][((t * 4 + 0) + lane) & 31] = accT[t].x;
        s_part[wave][lane][((t * 4 + 1) + lane) & 31] = accT[t].y;
        s_part[wave][lane][((t * 4 + 2) + lane) & 31] = accT[t].z;
        s_part[wave][lane][((t * 4 + 3) + lane) & 31] = accT[t].w;
    }
    __syncthreads();
    for (int idx = threadIdx.x; idx < 2048; idx += 256) {
        int L = idx >> 5, e = idx & 31;
        float v = 0.f;
#pragma unroll
        for (int w = 0; w < 4; ++w) v += s_part[w][L][(e + L) & 31];
        int t = e >> 2, bi = e & 3;
        int b = bt * 256 + L * 4 + bi;
        part[((size_t)g * BATCH + b) * NTGT + t] = v;
    }
}

// out[b][t] = b2[t] + sum_g part[g][b][t]
__global__ void k_reduce(const float* __restrict__ part, const float* __restrict__ b2,
                         float* __restrict__ out) {
    int i = blockIdx.x * blockDim.x + threadIdx.x;  // b*8+t over 32768
    if (i >= BATCH * NTGT) return;
    int t = i & 7;
    float v = b2[t];
#pragma unroll
    for (int g = 0; g < 32; ++g) v += part[(size_t)g * BATCH * NTGT + i];
    out[i] = v;
}

extern "C" void kernel_launch(void* const* d_in, const int* in_sizes, int n_in,
                              void* d_out, int out_size, void* d_ws, size_t ws_size,
                              hipStream_t stream) {
    (void)in_sizes; (void)n_in; (void)out_size; (void)ws_size;
    const float* x   = (const float*)d_in[0];
    const float* w1  = (const float*)d_in[1];
    const float* b1  = (const float*)d_in[2];
    const float* w2  = (const float*)d_in[3];
    const float* b2  = (const float*)d_in[4];
    const int*   c1o = (const int*)d_in[5];
    const int*   c1i = (const int*)d_in[6];
    const int*   c2o = (const int*)d_in[7];
    const int*   c2i = (const int*)d_in[8];
    float* out = (float*)d_out;

    char* ws = (char*)d_ws;
    float* xT   = (float*)(ws + OFF_XT);
    float* part = (float*)(ws + OFF_PART);
    Edge*  e1   = (Edge*)(ws + OFF_E1);
    float* W2d  = (float*)(ws + OFF_W2D);
    int*   rp1  = (int*)(ws + OFF_RP1);
    int*   cur1 = (int*)(ws + OFF_CUR1);
    int*   cnt1 = (int*)(ws + OFF_CNT1);

    // CSR build for layer 1 + dense W2
    k_zero<<<(NNEUR * NTGT + 255) / 256, 256, 0, stream>>>(cnt1, W2d);
    k_hist<<<(NNZ1 + NNZ2) / 256, 256, 0, stream>>>(c1o, c2o, c2i, w2, cnt1, W2d);
    k_scan<<<1, NNEUR, 0, stream>>>(cnt1, rp1, cur1);
    k_scatter<<<NNZ1 / 256, 256, 0, stream>>>(w1, c1o, c1i, cur1, e1);

    // transpose x for coalesced lane=batch gathers
    k_transpose<<<dim3(NFEAT / 64, BATCH / 64), dim3(16, 16), 0, stream>>>(x, xT);

    // fused layer1 + sigmoid + layer2 partials
    k_layer1_fused<<<512, 256, 0, stream>>>(e1, rp1, b1, W2d, xT, part);

    // final reduce
    k_reduce<<<BATCH * NTGT / 256, 256, 0, stream>>>(part, b2, out);
}

// Round 3
// 74.642 us; speedup vs baseline: 4.1243x; 1.8671x over previous
//
#include <hip/hip_runtime.h>
#include <math.h>

// Problem constants
#define BATCH 4096
#define NFEAT 2048
#define NNEUR 1024
#define NTGT  8
#define NNZ1  65536
#define NNZ2  8192

// GEMM: hT[m][n] = sigmoid( sum_k W1b[m][k] * xb[n][k] + b1[m] )
//   M = NNEUR (1024), N = BATCH (4096), K = NFEAT (2048)
#define BM 128
#define BN 128
#define BK 32

typedef short  bf16x8 __attribute__((ext_vector_type(8)));
typedef float  f32x4  __attribute__((ext_vector_type(4)));

// ---------------- workspace layout (bytes) ----------------
// W1f : [NNEUR][NFEAT] f32    8 MB   @ 0
// W1b : [NNEUR][NFEAT] bf16   4 MB   @ 8 MB
// xb  : [BATCH][NFEAT] bf16  16 MB   @ 12 MB
// hT  : [NNEUR][BATCH] f32   16 MB   @ 28 MB
// part: [16][BATCH][NTGT] f32 2 MB   @ 44 MB
// W2d : [NNEUR][NTGT] f32    32 KB   @ 46 MB
#define OFF_W1F  ((size_t)0)
#define OFF_W1B  ((size_t)8  << 20)
#define OFF_XB   ((size_t)12 << 20)
#define OFF_HT   ((size_t)28 << 20)
#define OFF_PART ((size_t)44 << 20)
#define OFF_W2D  ((size_t)46 << 20)

__device__ __forceinline__ unsigned short f2bf(float f) {
    union { float f; unsigned int u; } a; a.f = f;
    unsigned int u = a.u;
    u += 0x7fffu + ((u >> 16) & 1u);   // round-to-nearest-even
    return (unsigned short)(u >> 16);
}

__device__ __forceinline__ void load_lds16(const unsigned short* g, unsigned short* l) {
    __builtin_amdgcn_global_load_lds(
        (const __attribute__((address_space(1))) unsigned int*)g,
        (__attribute__((address_space(3))) unsigned int*)l,
        16, 0, 0);
}

// zero W1f (2M floats) and W2d (8192 floats); grid 8192x256 covers both exactly
__global__ void k_zero(float* __restrict__ W1f, float* __restrict__ W2d) {
    int i = blockIdx.x * blockDim.x + threadIdx.x;
    W1f[i] = 0.f;
    if (i < NNEUR * NTGT) W2d[i] = 0.f;
}

// scatter-add edges into dense W1f and W2d (handles duplicate edges by summing)
__global__ void k_build(const float* __restrict__ w1, const int* __restrict__ c1o,
                        const int* __restrict__ c1i,
                        const float* __restrict__ w2, const int* __restrict__ c2o,
                        const int* __restrict__ c2i,
                        float* __restrict__ W1f, float* __restrict__ W2d) {
    int i = blockIdx.x * blockDim.x + threadIdx.x;
    if (i < NNZ1) {
        atomicAdd(&W1f[(size_t)c1o[i] * NFEAT + c1i[i]], w1[i]);
    } else {
        int j = i - NNZ1;
        if (j < NNZ2) atomicAdd(&W2d[c2i[j] * NTGT + c2o[j]], w2[j]);
    }
}

// convert W1f -> W1b and x -> xb, float4 -> 4x bf16 per thread
__global__ void k_convert(const float* __restrict__ W1f, const float* __restrict__ x,
                          unsigned short* __restrict__ W1b, unsigned short* __restrict__ xb) {
    int i = blockIdx.x * blockDim.x + threadIdx.x;
    const int nW = NNEUR * NFEAT / 4;
    const int nX = BATCH * NFEAT / 4;
    if (i < nW) {
        float4 v = ((const float4*)W1f)[i];
        ushort4 o;
        o.x = f2bf(v.x); o.y = f2bf(v.y); o.z = f2bf(v.z); o.w = f2bf(v.w);
        ((ushort4*)W1b)[i] = o;
    } else if (i < nW + nX) {
        int j = i - nW;
        float4 v = ((const float4*)x)[j];
        ushort4 o;
        o.x = f2bf(v.x); o.y = f2bf(v.y); o.z = f2bf(v.z); o.w = f2bf(v.w);
        ((ushort4*)xb)[j] = o;
    }
}

// bf16 MFMA GEMM, m97-style: 128x128 tile, BK=32, global_load_lds(16B), 2-barrier loop.
// 512 threads = 8 waves (2 x 4); each wave computes 64x32 via 4x2 frags of 16x16x32.
// Epilogue: + b1[m], sigmoid, write hT[m][n] fp32 (coalesced along n).
__global__ __launch_bounds__(512) void k_gemm(const unsigned short* __restrict__ W1b,
                                              const unsigned short* __restrict__ xb,
                                              const float* __restrict__ b1,
                                              float* __restrict__ hT) {
    __shared__ unsigned short ldsA[BM * BK];   // 8 KB
    __shared__ unsigned short ldsB[BN * BK];   // 8 KB

    // bijective swizzle: each XCD gets a contiguous strip of 4 n-tiles (all m-tiles)
    int bid  = blockIdx.x;                 // 0..255
    int virt = (bid & 7) * 32 + (bid >> 3);
    int n0 = (virt >> 3) * BN;             // 32 n-tiles
    int m0 = (virt & 7) * BM;              // 8 m-tiles

    int tid  = threadIdx.x;
    int wv   = tid >> 6;
    int lane = tid & 63;
    int wm = wv >> 2, wn = wv & 3;         // wave grid 2 x 4
    int lr = lane & 15, lg = lane >> 4;

    f32x4 zero4 = {0.f, 0.f, 0.f, 0.f};
    f32x4 acc[4][2];
#pragma unroll
    for (int i = 0; i < 4; ++i)
#pragma unroll
        for (int j = 0; j < 2; ++j) acc[i][j] = zero4;

    // staging: thread t loads 16B: row = t>>2 (128 rows), k-off = (t&3)*8
    const unsigned short* gA = &W1b[(size_t)(m0 + (tid >> 2)) * NFEAT + (tid & 3) * 8];
    const unsigned short* gB = &xb [(size_t)(n0 + (tid >> 2)) * NFEAT + (tid & 3) * 8];
    unsigned short* lA = &ldsA[wv * 512];  // wave-uniform base; lane l lands at +l*16B
    unsigned short* lB = &ldsB[wv * 512];

    for (int k0 = 0; k0 < NFEAT; k0 += BK) {
        __syncthreads();                   // previous compute done before overwrite
        load_lds16(gA + k0, lA);
        load_lds16(gB + k0, lB);
        __syncthreads();                   // staged data visible (implies vmcnt(0))

        bf16x8 af[4], bg[2];
#pragma unroll
        for (int i = 0; i < 4; ++i)
            af[i] = *(const bf16x8*)&ldsA[(wm * 64 + i * 16 + lr) * BK + lg * 8];
#pragma unroll
        for (int j = 0; j < 2; ++j)
            bg[j] = *(const bf16x8*)&ldsB[(wn * 32 + j * 16 + lr) * BK + lg * 8];
#pragma unroll
        for (int i = 0; i < 4; ++i)
#pragma unroll
            for (int j = 0; j < 2; ++j)
                acc[i][j] = __builtin_amdgcn_mfma_f32_16x16x32_bf16(af[i], bg[j], acc[i][j], 0, 0, 0);
    }

    // epilogue: C/D layout col=lane&15 (n), row=(lane>>4)*4+reg (m)  [m89-verified]
#pragma unroll
    for (int i = 0; i < 4; ++i) {
        int mb = m0 + wm * 64 + i * 16 + lg * 4;
#pragma unroll
        for (int j = 0; j < 2; ++j) {
            int n = n0 + wn * 32 + j * 16 + lr;
#pragma unroll
            for (int r = 0; r < 4; ++r) {
                int m = mb + r;
                float z = acc[i][j][r] + b1[m];
                hT[(size_t)m * BATCH + n] = 1.f / (1.f + __expf(-z));
            }
        }
    }
}

// layer 2 partials: part[nc][b][t] = sum_{n in chunk nc} hT[n][b] * W2d[n][t]
// grid 256 blocks = 16 batch tiles (256 cols) x 16 neuron chunks (64 each)
__global__ __launch_bounds__(256) void k_layer2(const float* __restrict__ hT,
                                                const float* __restrict__ W2d,
                                                float* __restrict__ part) {
    int bt = blockIdx.x >> 4;
    int nc = blockIdx.x & 15;
    int b  = bt * 256 + threadIdx.x;
    float accT[NTGT];
#pragma unroll
    for (int t = 0; t < NTGT; ++t) accT[t] = 0.f;
    for (int ni = 0; ni < 64; ++ni) {
        int n = nc * 64 + ni;
        float h = hT[(size_t)n * BATCH + b];
        const float* w2r = &W2d[n * NTGT];
#pragma unroll
        for (int t = 0; t < NTGT; ++t) accT[t] += w2r[t] * h;
    }
#pragma unroll
    for (int t = 0; t < NTGT; ++t)
        part[((size_t)nc * BATCH + b) * NTGT + t] = accT[t];
}

// out[b][t] = b2[t] + sum_nc part[nc][b][t]
__global__ void k_reduce(const float* __restrict__ part, const float* __restrict__ b2,
                         float* __restrict__ out) {
    int i = blockIdx.x * blockDim.x + threadIdx.x;  // 32768
    float v = b2[i & 7];
#pragma unroll
    for (int c = 0; c < 16; ++c) v += part[(size_t)c * BATCH * NTGT + i];
    out[i] = v;
}

extern "C" void kernel_launch(void* const* d_in, const int* in_sizes, int n_in,
                              void* d_out, int out_size, void* d_ws, size_t ws_size,
                              hipStream_t stream) {
    (void)in_sizes; (void)n_in; (void)out_size; (void)ws_size;
    const float* x   = (const float*)d_in[0];
    const float* w1  = (const float*)d_in[1];
    const float* b1  = (const float*)d_in[2];
    const float* w2  = (const float*)d_in[3];
    const float* b2  = (const float*)d_in[4];
    const int*   c1o = (const int*)d_in[5];
    const int*   c1i = (const int*)d_in[6];
    const int*   c2o = (const int*)d_in[7];
    const int*   c2i = (const int*)d_in[8];
    float* out = (float*)d_out;

    char* ws = (char*)d_ws;
    float*          W1f  = (float*)(ws + OFF_W1F);
    unsigned short* W1b  = (unsigned short*)(ws + OFF_W1B);
    unsigned short* xb   = (unsigned short*)(ws + OFF_XB);
    float*          hT   = (float*)(ws + OFF_HT);
    float*          part = (float*)(ws + OFF_PART);
    float*          W2d  = (float*)(ws + OFF_W2D);

    // dense weight build
    k_zero<<<NNEUR * NFEAT / 256, 256, 0, stream>>>(W1f, W2d);
    k_build<<<(NNZ1 + NNZ2) / 256, 256, 0, stream>>>(w1, c1o, c1i, w2, c2o, c2i, W1f, W2d);

    // fp32 -> bf16 for MFMA operands
    k_convert<<<(NNEUR * NFEAT / 4 + BATCH * NFEAT / 4) / 256, 256, 0, stream>>>(W1f, x, W1b, xb);

    // layer 1 as dense bf16 MFMA GEMM (+bias+sigmoid fused)
    k_gemm<<<(NNEUR / BM) * (BATCH / BN), 512, 0, stream>>>(W1b, xb, b1, hT);

    // layer 2 (effectively dense, fp32) + final reduce
    k_layer2<<<16 * 16, 256, 0, stream>>>(hT, W2d, part);
    k_reduce<<<BATCH * NTGT / 256, 256, 0, stream>>>(part, b2, out);
}

// Round 4
// 59.584 us; speedup vs baseline: 5.1666x; 1.2527x over previous
//
#include <hip/hip_runtime.h>
#include <math.h>

// Problem constants
#define BATCH 4096
#define NFEAT 2048
#define NNEUR 1024
#define NTGT  8
#define NNZ1  65536
#define NNZ2  8192

// GEMM: h[m][n] = sigmoid( sum_k W1b[m][k] * xb[n][k] + b1[m] ), fused layer-2 partials
//   M = NNEUR (1024), N = BATCH (4096), K = NFEAT (2048)
#define BM 128
#define BN 128
#define BK 32
#define KITERS (NFEAT / BK)

typedef short  bf16x8 __attribute__((ext_vector_type(8)));
typedef float  f32x4  __attribute__((ext_vector_type(4)));

// ---------------- workspace layout (bytes) ----------------
// W1f : [NNEUR][NFEAT] f32    8 MB     @ 0
// W2d : [NNEUR][NTGT] f32    32 KB     @ 8 MB        (zeroed together with W1f in one memset)
// W1b : [NNEUR][NFEAT] bf16   4 MB     @ 8 MB+32KB
// xb  : [BATCH][NFEAT] bf16  16 MB     @ 12 MB+32KB
// part: [8][BATCH][NTGT] f32  1 MB     @ 28 MB+32KB
#define OFF_W1F  ((size_t)0)
#define OFF_W2D  ((size_t)8388608)
#define OFF_W1B  ((size_t)8421376)
#define OFF_XB   ((size_t)12615680)
#define OFF_PART ((size_t)29392896)

__device__ __forceinline__ unsigned short f2bf(float f) {
    union { float f; unsigned int u; } a; a.f = f;
    unsigned int u = a.u;
    u += 0x7fffu + ((u >> 16) & 1u);   // round-to-nearest-even
    return (unsigned short)(u >> 16);
}

__device__ __forceinline__ void load_lds16(const unsigned short* g, unsigned short* l) {
    __builtin_amdgcn_global_load_lds(
        (const __attribute__((address_space(1))) unsigned int*)g,
        (__attribute__((address_space(3))) unsigned int*)l,
        16, 0, 0);
}

// scatter-add edges into dense W1f and W2d (handles duplicate edges by summing)
__global__ void k_build(const float* __restrict__ w1, const int* __restrict__ c1o,
                        const int* __restrict__ c1i,
                        const float* __restrict__ w2, const int* __restrict__ c2o,
                        const int* __restrict__ c2i,
                        float* __restrict__ W1f, float* __restrict__ W2d) {
    int i = blockIdx.x * blockDim.x + threadIdx.x;
    if (i < NNZ1) {
        atomicAdd(&W1f[(size_t)c1o[i] * NFEAT + c1i[i]], w1[i]);
    } else {
        int j = i - NNZ1;
        if (j < NNZ2) atomicAdd(&W2d[c2i[j] * NTGT + c2o[j]], w2[j]);
    }
}

// convert W1f -> W1b and x -> xb, float4 -> 4x bf16 per thread
__global__ void k_convert(const float* __restrict__ W1f, const float* __restrict__ x,
                          unsigned short* __restrict__ W1b, unsigned short* __restrict__ xb) {
    int i = blockIdx.x * blockDim.x + threadIdx.x;
    const int nW = NNEUR * NFEAT / 4;
    const int nX = BATCH * NFEAT / 4;
    if (i < nW) {
        float4 v = ((const float4*)W1f)[i];
        ushort4 o;
        o.x = f2bf(v.x); o.y = f2bf(v.y); o.z = f2bf(v.z); o.w = f2bf(v.w);
        ((ushort4*)W1b)[i] = o;
    } else if (i < nW + nX) {
        int j = i - nW;
        float4 v = ((const float4*)x)[j];
        ushort4 o;
        o.x = f2bf(v.x); o.y = f2bf(v.y); o.z = f2bf(v.z); o.w = f2bf(v.w);
        ((ushort4*)xb)[j] = o;
    }
}

// bf16 MFMA GEMM with fused bias+sigmoid+layer2-partial epilogue.
// 128x128 tile, BK=32, double-buffered LDS, global_load_lds(16B) with
// pre-swizzled k-slot (bank-conflict-free ds_read_b128), ONE barrier per K-iter.
// 512 threads = 8 waves (2m x 4n); wave computes 64x32 via 4x2 frags of 16x16x32.
__global__ __launch_bounds__(512) void k_gemm(const unsigned short* __restrict__ W1b,
                                              const unsigned short* __restrict__ xb,
                                              const float* __restrict__ b1,
                                              const float* __restrict__ W2d,
                                              float* __restrict__ partial) {
    __shared__ unsigned short ldsA[2][BM * BK];   // 2 x 8 KB
    __shared__ unsigned short ldsB[2][BN * BK];   // 2 x 8 KB
    __shared__ float s_w2[BM][NTGT];              // 4 KB
    __shared__ float s_b1[BM];                    // 512 B
    __shared__ float s_pt[2][BN][NTGT];           // 8 KB

    // bijective XCD swizzle: each XCD gets 4 n-tiles x all 8 m-tiles
    int bid  = blockIdx.x;                 // 0..255
    int virt = (bid & 7) * 32 + (bid >> 3);
    int n0 = (virt >> 3) * BN;             // 32 n-tiles
    int mt = virt & 7;                     // 8 m-tiles
    int m0 = mt * BM;

    int tid  = threadIdx.x;
    int wv   = tid >> 6;
    int lane = tid & 63;
    int wm = wv >> 2, wn = wv & 3;         // wave grid 2 x 4
    int lr = lane & 15, lg = lane >> 4;

    // preload W2d + b1 slices for the epilogue
    for (int i = tid; i < BM * NTGT; i += 512)
        s_w2[i >> 3][i & 7] = W2d[(m0 + (i >> 3)) * NTGT + (i & 7)];
    if (tid < BM) s_b1[tid] = b1[m0 + tid];

    f32x4 zero4 = {0.f, 0.f, 0.f, 0.f};
    f32x4 acc[4][2];
#pragma unroll
    for (int i = 0; i < 4; ++i)
#pragma unroll
        for (int j = 0; j < 2; ++j) acc[i][j] = zero4;

    // staging: thread t -> LDS unit t (linear dest). row = t>>2 (128 rows),
    // global k-slot = (t&3) ^ ((row>>1)&3)  [pre-swizzled source, rule #21]
    int srow  = tid >> 2;
    int kslot = (tid & 3) ^ ((tid >> 3) & 3);
    const unsigned short* gA = &W1b[(size_t)(m0 + srow) * NFEAT + kslot * 8];
    const unsigned short* gB = &xb [(size_t)(n0 + srow) * NFEAT + kslot * 8];
    unsigned short* lA0 = &ldsA[0][wv * 512];   // wave-uniform base; lane lands at +lane*16B
    unsigned short* lB0 = &ldsB[0][wv * 512];
    unsigned short* lA1 = &ldsA[1][wv * 512];
    unsigned short* lB1 = &ldsB[1][wv * 512];

    // read-side swizzle: unit = row*4 + (lg ^ ((row>>1)&3)); row>>1&3 == lr>>1&3 here
    int swz = (lg ^ ((lr >> 1) & 3)) * 8;

    // prologue: stage tile 0 into buf 0
    load_lds16(gA, lA0);
    load_lds16(gB, lB0);
    __syncthreads();

    int cur = 0;
    for (int t = 0; t < KITERS; ++t) {
        // stage next tile into the other buffer (overlaps with this tile's MFMA)
        if (t + 1 < KITERS) {
            int k0 = (t + 1) * BK;
            load_lds16(gA + k0, cur ? lA0 : lA1);
            load_lds16(gB + k0, cur ? lB0 : lB1);
        }
        const unsigned short* bA = ldsA[cur];
        const unsigned short* bB = ldsB[cur];
        bf16x8 af[4], bg[2];
#pragma unroll
        for (int i = 0; i < 4; ++i)
            af[i] = *(const bf16x8*)&bA[(wm * 64 + i * 16 + lr) * BK + swz];
#pragma unroll
        for (int j = 0; j < 2; ++j)
            bg[j] = *(const bf16x8*)&bB[(wn * 32 + j * 16 + lr) * BK + swz];
#pragma unroll
        for (int i = 0; i < 4; ++i)
#pragma unroll
            for (int j = 0; j < 2; ++j)
                acc[i][j] = __builtin_amdgcn_mfma_f32_16x16x32_bf16(af[i], bg[j], acc[i][j], 0, 0, 0);
        __syncthreads();   // drains stage (vmcnt) + all waves done reading buf[cur]
        cur ^= 1;
    }

    // ---- fused epilogue: h = sigmoid(acc + b1); pt[j][t] = sum_m h * W2d[m][t] ----
    // C/D layout: col(n) = lane&15, row(m) = (lane>>4)*4 + reg   [m89-verified]
    float pt[2][NTGT];
#pragma unroll
    for (int j = 0; j < 2; ++j)
#pragma unroll
        for (int t = 0; t < NTGT; ++t) pt[j][t] = 0.f;

#pragma unroll
    for (int i = 0; i < 4; ++i) {
#pragma unroll
        for (int r = 0; r < 4; ++r) {
            int ml = wm * 64 + i * 16 + lg * 4 + r;
            float bn = s_b1[ml];
#pragma unroll
            for (int j = 0; j < 2; ++j) {
                float h = 1.f / (1.f + __expf(-(acc[i][j][r] + bn)));
#pragma unroll
                for (int t = 0; t < NTGT; ++t)
                    pt[j][t] += h * s_w2[ml][t];
            }
        }
    }
    // reduce over lg (lanes lr+16*lg share the same n column)
#pragma unroll
    for (int j = 0; j < 2; ++j)
#pragma unroll
        for (int t = 0; t < NTGT; ++t) {
            float v = pt[j][t];
            v += __shfl_xor(v, 16, 64);
            v += __shfl_xor(v, 32, 64);
            pt[j][t] = v;
        }
    if (lg == 0) {
#pragma unroll
        for (int j = 0; j < 2; ++j) {
            int nl = wn * 32 + j * 16 + lr;
#pragma unroll
            for (int t = 0; t < NTGT; ++t)
                s_pt[wm][nl][t] = pt[j][t];
        }
    }
    __syncthreads();
    // partial[mt][n][t], 128 n x 8 t per block
    for (int idx = tid; idx < BN * NTGT; idx += 512) {
        int nl = idx >> 3, t = idx & 7;
        partial[((size_t)mt * BATCH + (n0 + nl)) * NTGT + t] = s_pt[0][nl][t] + s_pt[1][nl][t];
    }
}

// out[b][t] = b2[t] + sum_mt partial[mt][b][t]
__global__ void k_reduce(const float* __restrict__ partial, const float* __restrict__ b2,
                         float* __restrict__ out) {
    int i = blockIdx.x * blockDim.x + threadIdx.x;  // 32768
    float v = b2[i & 7];
#pragma unroll
    for (int c = 0; c < 8; ++c) v += partial[(size_t)c * BATCH * NTGT + i];
    out[i] = v;
}

extern "C" void kernel_launch(void* const* d_in, const int* in_sizes, int n_in,
                              void* d_out, int out_size, void* d_ws, size_t ws_size,
                              hipStream_t stream) {
    (void)in_sizes; (void)n_in; (void)out_size; (void)ws_size;
    const float* x   = (const float*)d_in[0];
    const float* w1  = (const float*)d_in[1];
    const float* b1  = (const float*)d_in[2];
    const float* w2  = (const float*)d_in[3];
    const float* b2  = (const float*)d_in[4];
    const int*   c1o = (const int*)d_in[5];
    const int*   c1i = (const int*)d_in[6];
    const int*   c2o = (const int*)d_in[7];
    const int*   c2i = (const int*)d_in[8];
    float* out = (float*)d_out;

    char* ws = (char*)d_ws;
    float*          W1f  = (float*)(ws + OFF_W1F);
    float*          W2d  = (float*)(ws + OFF_W2D);
    unsigned short* W1b  = (unsigned short*)(ws + OFF_W1B);
    unsigned short* xb   = (unsigned short*)(ws + OFF_XB);
    float*          part = (float*)(ws + OFF_PART);

    // zero W1f + W2d (adjacent) in one async memset (graph-capture safe)
    hipMemsetAsync(ws + OFF_W1F, 0, OFF_W2D - OFF_W1F + (size_t)NNEUR * NTGT * 4, stream);

    // dense weight build
    k_build<<<(NNZ1 + NNZ2) / 256, 256, 0, stream>>>(w1, c1o, c1i, w2, c2o, c2i, W1f, W2d);

    // fp32 -> bf16 for MFMA operands
    k_convert<<<(NNEUR * NFEAT / 4 + BATCH * NFEAT / 4) / 256, 256, 0, stream>>>(W1f, x, W1b, xb);

    // layer 1 GEMM + bias + sigmoid + layer-2 partials, all fused
    k_gemm<<<(NNEUR / BM) * (BATCH / BN), 512, 0, stream>>>(W1b, xb, b1, W2d, part);

    // final reduce over the 8 m-tiles
    k_reduce<<<BATCH * NTGT / 256, 256, 0, stream>>>(part, b2, out);
}

// Round 5
// 59.041 us; speedup vs baseline: 5.2141x; 1.0092x over previous
//
#include <hip/hip_runtime.h>
#include <math.h>

// Problem constants
#define BATCH 4096
#define NFEAT 2048
#define NNEUR 1024
#define NTGT  8
#define NNZ1  65536
#define NNZ2  8192

// GEMM: h[m][n] = sigmoid( sum_k W1b[m][k] * xb[n][k] + b1[m] ), fused layer-2 partials
//   M = NNEUR (1024), N = BATCH (4096), K = NFEAT (2048)
#define BM 128
#define BN 128
#define BK 32
#define KITERS (NFEAT / BK)

typedef short  bf16x8 __attribute__((ext_vector_type(8)));
typedef float  f32x4  __attribute__((ext_vector_type(4)));

// ---------------- workspace layout (bytes) ----------------
// W1f : [NNEUR][NFEAT] f32    8 MB     @ 0
// W2d : [NNEUR][NTGT] f32    32 KB     @ 8 MB        (zeroed together with W1f)
// W1b : [NNEUR][NFEAT] bf16   4 MB     @ 8 MB+32KB
// xb  : [BATCH][NFEAT] bf16  16 MB     @ 12 MB+32KB
// part: [8][BATCH][NTGT] f32  1 MB     @ 28 MB+32KB
#define OFF_W1F  ((size_t)0)
#define OFF_W2D  ((size_t)8388608)
#define OFF_W1B  ((size_t)8421376)
#define OFF_XB   ((size_t)12615680)
#define OFF_PART ((size_t)29392896)

// W1f + W2d are contiguous: 8421376 B = 526336 float4 = 2056 blocks x 256 thr
#define ZERO_FLOAT4 526336

__device__ __forceinline__ unsigned short f2bf(float f) {
    union { float f; unsigned int u; } a; a.f = f;
    unsigned int u = a.u;
    u += 0x7fffu + ((u >> 16) & 1u);   // round-to-nearest-even
    return (unsigned short)(u >> 16);
}

__device__ __forceinline__ void load_lds16(const unsigned short* g, unsigned short* l) {
    __builtin_amdgcn_global_load_lds(
        (const __attribute__((address_space(1))) unsigned int*)g,
        (__attribute__((address_space(3))) unsigned int*)l,
        16, 0, 0);
}

// fast zero of W1f+W2d: one float4 store per thread (rocclr fill ran at 200 GB/s)
__global__ void k_zero4(float4* __restrict__ p) {
    int i = blockIdx.x * blockDim.x + threadIdx.x;
    p[i] = make_float4(0.f, 0.f, 0.f, 0.f);
}

// scatter-add edges into dense W1f and W2d (handles duplicate edges by summing)
__global__ void k_build(const float* __restrict__ w1, const int* __restrict__ c1o,
                        const int* __restrict__ c1i,
                        const float* __restrict__ w2, const int* __restrict__ c2o,
                        const int* __restrict__ c2i,
                        float* __restrict__ W1f, float* __restrict__ W2d) {
    int i = blockIdx.x * blockDim.x + threadIdx.x;
    if (i < NNZ1) {
        atomicAdd(&W1f[(size_t)c1o[i] * NFEAT + c1i[i]], w1[i]);
    } else {
        int j = i - NNZ1;
        if (j < NNZ2) atomicAdd(&W2d[c2i[j] * NTGT + c2o[j]], w2[j]);
    }
}

// convert W1f -> W1b and x -> xb, float4 -> 4x bf16 per thread
__global__ void k_convert(const float* __restrict__ W1f, const float* __restrict__ x,
                          unsigned short* __restrict__ W1b, unsigned short* __restrict__ xb) {
    int i = blockIdx.x * blockDim.x + threadIdx.x;
    const int nW = NNEUR * NFEAT / 4;
    const int nX = BATCH * NFEAT / 4;
    if (i < nW) {
        float4 v = ((const float4*)W1f)[i];
        ushort4 o;
        o.x = f2bf(v.x); o.y = f2bf(v.y); o.z = f2bf(v.z); o.w = f2bf(v.w);
        ((ushort4*)W1b)[i] = o;
    } else if (i < nW + nX) {
        int j = i - nW;
        float4 v = ((const float4*)x)[j];
        ushort4 o;
        o.x = f2bf(v.x); o.y = f2bf(v.y); o.z = f2bf(v.z); o.w = f2bf(v.w);
        ((ushort4*)xb)[j] = o;
    }
}

// bf16 MFMA GEMM with fused bias+sigmoid+layer2-partial epilogue.
// 128x128 tile, BK=32, double-buffered LDS, global_load_lds(16B) with
// pre-swizzled k-slot (bank-conflict-free ds_read_b128), ONE barrier per K-iter.
// 512 threads = 8 waves (2m x 4n); wave computes 64x32 via 4x2 frags of 16x16x32.
__global__ __launch_bounds__(512) void k_gemm(const unsigned short* __restrict__ W1b,
                                              const unsigned short* __restrict__ xb,
                                              const float* __restrict__ b1,
                                              const float* __restrict__ W2d,
                                              float* __restrict__ partial) {
    __shared__ unsigned short ldsA[2][BM * BK];   // 2 x 8 KB
    __shared__ unsigned short ldsB[2][BN * BK];   // 2 x 8 KB
    __shared__ float s_w2[BM][NTGT];              // 4 KB
    __shared__ float s_b1[BM];                    // 512 B
    __shared__ float s_pt[2][BN][NTGT];           // 8 KB

    // bijective XCD swizzle: each XCD gets 4 n-tiles x all 8 m-tiles
    int bid  = blockIdx.x;                 // 0..255
    int virt = (bid & 7) * 32 + (bid >> 3);
    int n0 = (virt >> 3) * BN;             // 32 n-tiles
    int mt = virt & 7;                     // 8 m-tiles
    int m0 = mt * BM;

    int tid  = threadIdx.x;
    int wv   = tid >> 6;
    int lane = tid & 63;
    int wm = wv >> 2, wn = wv & 3;         // wave grid 2 x 4
    int lr = lane & 15, lg = lane >> 4;

    // preload W2d + b1 slices for the epilogue
    for (int i = tid; i < BM * NTGT; i += 512)
        s_w2[i >> 3][i & 7] = W2d[(m0 + (i >> 3)) * NTGT + (i & 7)];
    if (tid < BM) s_b1[tid] = b1[m0 + tid];

    f32x4 zero4 = {0.f, 0.f, 0.f, 0.f};
    f32x4 acc[4][2];
#pragma unroll
    for (int i = 0; i < 4; ++i)
#pragma unroll
        for (int j = 0; j < 2; ++j) acc[i][j] = zero4;

    // staging: thread t -> LDS unit t (linear dest). row = t>>2 (128 rows),
    // global k-slot = (t&3) ^ ((row>>1)&3)  [pre-swizzled source, rule #21]
    int srow  = tid >> 2;
    int kslot = (tid & 3) ^ ((tid >> 3) & 3);
    const unsigned short* gA = &W1b[(size_t)(m0 + srow) * NFEAT + kslot * 8];
    const unsigned short* gB = &xb [(size_t)(n0 + srow) * NFEAT + kslot * 8];
    unsigned short* lA0 = &ldsA[0][wv * 512];   // wave-uniform base; lane lands at +lane*16B
    unsigned short* lB0 = &ldsB[0][wv * 512];
    unsigned short* lA1 = &ldsA[1][wv * 512];
    unsigned short* lB1 = &ldsB[1][wv * 512];

    // read-side swizzle: unit = row*4 + (lg ^ ((row>>1)&3)); row>>1&3 == lr>>1&3 here
    int swz = (lg ^ ((lr >> 1) & 3)) * 8;

    // prologue: stage tile 0 into buf 0
    load_lds16(gA, lA0);
    load_lds16(gB, lB0);
    __syncthreads();

    int cur = 0;
    for (int t = 0; t < KITERS; ++t) {
        // stage next tile into the other buffer (overlaps with this tile's MFMA)
        if (t + 1 < KITERS) {
            int k0 = (t + 1) * BK;
            load_lds16(gA + k0, cur ? lA0 : lA1);
            load_lds16(gB + k0, cur ? lB0 : lB1);
        }
        const unsigned short* bA = ldsA[cur];
        const unsigned short* bB = ldsB[cur];
        bf16x8 af[4], bg[2];
#pragma unroll
        for (int i = 0; i < 4; ++i)
            af[i] = *(const bf16x8*)&bA[(wm * 64 + i * 16 + lr) * BK + swz];
#pragma unroll
        for (int j = 0; j < 2; ++j)
            bg[j] = *(const bf16x8*)&bB[(wn * 32 + j * 16 + lr) * BK + swz];
#pragma unroll
        for (int i = 0; i < 4; ++i)
#pragma unroll
            for (int j = 0; j < 2; ++j)
                acc[i][j] = __builtin_amdgcn_mfma_f32_16x16x32_bf16(af[i], bg[j], acc[i][j], 0, 0, 0);
        __syncthreads();   // drains stage (vmcnt) + all waves done reading buf[cur]
        cur ^= 1;
    }

    // ---- fused epilogue: h = sigmoid(acc + b1); pt[j][t] = sum_m h * W2d[m][t] ----
    // C/D layout: col(n) = lane&15, row(m) = (lane>>4)*4 + reg   [m89-verified]
    float pt[2][NTGT];
#pragma unroll
    for (int j = 0; j < 2; ++j)
#pragma unroll
        for (int t = 0; t < NTGT; ++t) pt[j][t] = 0.f;

#pragma unroll
    for (int i = 0; i < 4; ++i) {
#pragma unroll
        for (int r = 0; r < 4; ++r) {
            int ml = wm * 64 + i * 16 + lg * 4 + r;
            float bn = s_b1[ml];
#pragma unroll
            for (int j = 0; j < 2; ++j) {
                float h = 1.f / (1.f + __expf(-(acc[i][j][r] + bn)));
#pragma unroll
                for (int t = 0; t < NTGT; ++t)
                    pt[j][t] += h * s_w2[ml][t];
            }
        }
    }
    // reduce over lg (lanes lr+16*lg share the same n column)
#pragma unroll
    for (int j = 0; j < 2; ++j)
#pragma unroll
        for (int t = 0; t < NTGT; ++t) {
            float v = pt[j][t];
            v += __shfl_xor(v, 16, 64);
            v += __shfl_xor(v, 32, 64);
            pt[j][t] = v;
        }
    if (lg == 0) {
#pragma unroll
        for (int j = 0; j < 2; ++j) {
            int nl = wn * 32 + j * 16 + lr;
#pragma unroll
            for (int t = 0; t < NTGT; ++t)
                s_pt[wm][nl][t] = pt[j][t];
        }
    }
    __syncthreads();
    // partial[mt][n][t], 128 n x 8 t per block
    for (int idx = tid; idx < BN * NTGT; idx += 512) {
        int nl = idx >> 3, t = idx & 7;
        partial[((size_t)mt * BATCH + (n0 + nl)) * NTGT + t] = s_pt[0][nl][t] + s_pt[1][nl][t];
    }
}

// out[b][t] = b2[t] + sum_mt partial[mt][b][t]
__global__ void k_reduce(const float* __restrict__ partial, const float* __restrict__ b2,
                         float* __restrict__ out) {
    int i = blockIdx.x * blockDim.x + threadIdx.x;  // 32768
    float v = b2[i & 7];
#pragma unroll
    for (int c = 0; c < 8; ++c) v += partial[(size_t)c * BATCH * NTGT + i];
    out[i] = v;
}

extern "C" void kernel_launch(void* const* d_in, const int* in_sizes, int n_in,
                              void* d_out, int out_size, void* d_ws, size_t ws_size,
                              hipStream_t stream) {
    (void)in_sizes; (void)n_in; (void)out_size; (void)ws_size;
    const float* x   = (const float*)d_in[0];
    const float* w1  = (const float*)d_in[1];
    const float* b1  = (const float*)d_in[2];
    const float* w2  = (const float*)d_in[3];
    const float* b2  = (const float*)d_in[4];
    const int*   c1o = (const int*)d_in[5];
    const int*   c1i = (const int*)d_in[6];
    const int*   c2o = (const int*)d_in[7];
    const int*   c2i = (const int*)d_in[8];
    float* out = (float*)d_out;

    char* ws = (char*)d_ws;
    float*          W1f  = (float*)(ws + OFF_W1F);
    float*          W2d  = (float*)(ws + OFF_W2D);
    unsigned short* W1b  = (unsigned short*)(ws + OFF_W1B);
    unsigned short* xb   = (unsigned short*)(ws + OFF_XB);
    float*          part = (float*)(ws + OFF_PART);

    // zero W1f + W2d with a custom vectorized kernel (rocclr fill was 41 us @ 200 GB/s)
    k_zero4<<<ZERO_FLOAT4 / 256, 256, 0, stream>>>((float4*)ws);

    // dense weight build
    k_build<<<(NNZ1 + NNZ2) / 256, 256, 0, stream>>>(w1, c1o, c1i, w2, c2o, c2i, W1f, W2d);

    // fp32 -> bf16 for MFMA operands
    k_convert<<<(NNEUR * NFEAT / 4 + BATCH * NFEAT / 4) / 256, 256, 0, stream>>>(W1f, x, W1b, xb);

    // layer 1 GEMM + bias + sigmoid + layer-2 partials, all fused
    k_gemm<<<(NNEUR / BM) * (BATCH / BN), 512, 0, stream>>>(W1b, xb, b1, W2d, part);

    // final reduce over the 8 m-tiles
    k_reduce<<<BATCH * NTGT / 256, 256, 0, stream>>>(part, b2, out);
}